// Round 10
// baseline (162.641 us; speedup 1.0000x reference)
//
#include <hip/hip_runtime.h>
#include <hip/hip_bf16.h>
#include <cstdint>
#include <cstddef>

// RGCN layer: out = (x@W0 + sum_r h_r@W[r]) / max(deg,1)
// Structure (round-9) + round-10 deltas:
//   k_gemm2: B-frags direct-from-L2 to registers (prefetched 1 step ahead);
//            only A goes through gl_lds double-buffer. LDS 48->16 KB.
//   k_agg:   8-deep gather unroll (more MLP), nontemporal h_cat stores.

#define NDIM 128
#define NREL 8
#define KCAT 1152        // 9*128
#define COARSE 196       // dst>>8 buckets
#define EPB 4096         // edges per hist/cscatter block

typedef __attribute__((ext_vector_type(8))) short bf16x8;
typedef __attribute__((ext_vector_type(4))) float f32x4;
typedef unsigned int uint32;

__device__ __forceinline__ short f2bf(float f){
  __hip_bfloat16 h = __float2bfloat16(f);
  return *reinterpret_cast<short*>(&h);
}
__device__ __forceinline__ float bfl(uint32 v){ return __uint_as_float(v << 16); }
__device__ __forceinline__ float bfh(uint32 v){ return __uint_as_float(v & 0xFFFF0000u); }

__device__ __forceinline__ void gload_lds16(const void* g, void* l){
  __builtin_amdgcn_global_load_lds(
      (const __attribute__((address_space(1))) unsigned int*)g,
      (__attribute__((address_space(3))) unsigned int*)l, 16, 0, 0);
}

// ---------- K1: casts + zero coarse_cnt + detect ----------
__global__ void k_prep(const float* __restrict__ x, uint32* __restrict__ xb, int n4, int xblocks,
                       const float* __restrict__ W, const float* __restrict__ W0,
                       short* __restrict__ Wb, int wblocks,
                       const int* __restrict__ ei, int* flag, int* coarse_cnt){
  int b = blockIdx.x;
  if (b < xblocks){
    int i = b * 256 + threadIdx.x;
    if (i >= n4) return;
    float4 f = ((const float4*)x)[i];
    uint32 lo = ((uint32)(unsigned short)f2bf(f.x)) | (((uint32)(unsigned short)f2bf(f.y)) << 16);
    uint32 hi = ((uint32)(unsigned short)f2bf(f.z)) | (((uint32)(unsigned short)f2bf(f.w)) << 16);
    ((uint2*)xb)[i] = make_uint2(lo, hi);
  } else if (b < xblocks + wblocks){
    int i = (b - xblocks) * 256 + threadIdx.x;
    if (i >= NDIM * KCAT) return;
    int j  = i / KCAT;
    int t  = i - j * KCAT;
    int r  = t >> 7;
    int kd = t & 127;
    float v = (r < NREL) ? W[(((size_t)r * NDIM + kd) << 7) + j] : W0[((size_t)kd << 7) + j];
    Wb[i] = f2bf(v);
  } else {
    if (threadIdx.x < COARSE) coarse_cnt[threadIdx.x] = 0;
    if (threadIdx.x < 64){
      int v = ei[2 * threadIdx.x + 1];
      unsigned long long m = __ballot(v == 0);
      if (threadIdx.x == 0) flag[0] = (m == ~0ull) ? 1 : 0;
    }
  }
}

// ---------- K2: decode + pack + coarse LDS hist + block reservations ----------
__global__ __launch_bounds__(1024) void k_hist(
    const int* __restrict__ ei, const int* __restrict__ et, const int* __restrict__ flag,
    uint32* __restrict__ kv, unsigned char* __restrict__ ctmp,
    int* __restrict__ coarse_cnt, int* __restrict__ blockRes, int E){
  __shared__ int h[COARSE];
  const int b = blockIdx.x;
  for (int i = threadIdx.x; i < COARSE; i += 1024) h[i] = 0;
  __syncthreads();
  const int is64 = flag[0];
  const int e0 = b * EPB;
  for (int i = threadIdx.x; i < EPB; i += 1024){
    int e = e0 + i;
    if (e < E){
      int s, d, t;
      if (is64){ s = ei[2*e]; d = ei[2*(E + e)]; t = et[2*e]; }
      else     { s = ei[e];   d = ei[E + e];     t = et[e];   }
      int c = d >> 8;
      kv[e]   = (uint32)s | ((uint32)t << 16) | ((uint32)(d & 255) << 19);
      ctmp[e] = (unsigned char)c;
      atomicAdd(&h[c], 1);
    }
  }
  __syncthreads();
  for (int c = threadIdx.x; c < COARSE; c += 1024){
    int cnt = h[c];
    int res = 0;
    if (cnt > 0) res = atomicAdd(&coarse_cnt[c], cnt);
    blockRes[b * COARSE + c] = res;
  }
}

// ---------- K3: scan coarse counts -> base ----------
__global__ void k_base(const int* __restrict__ coarse_cnt, int* __restrict__ base){
  __shared__ int sm[256];
  int t = threadIdx.x;
  int v = (t < COARSE) ? coarse_cnt[t] : 0;
  sm[t] = v; __syncthreads();
  #pragma unroll
  for (int off = 1; off < 256; off <<= 1){
    int xv = 0; if (t >= off) xv = sm[t - off];
    __syncthreads(); sm[t] += xv; __syncthreads();
  }
  if (t <= COARSE) base[t] = sm[t] - v;
}

// ---------- K4: coarse scatter (LDS cursors) ----------
__global__ __launch_bounds__(1024) void k_cscatter(
    const uint32* __restrict__ kv, const unsigned char* __restrict__ ctmp,
    const int* __restrict__ base, const int* __restrict__ blockRes,
    uint32* __restrict__ ckv, int E){
  __shared__ int cur[COARSE];
  const int b = blockIdx.x;
  for (int c = threadIdx.x; c < COARSE; c += 1024)
    cur[c] = base[c] + blockRes[b * COARSE + c];
  __syncthreads();
  const int e0 = b * EPB;
  for (int i = threadIdx.x; i < EPB; i += 1024){
    int e = e0 + i;
    if (e < E){
      uint32 v = kv[e];
      int c = ctmp[e];
      int pos = atomicAdd(&cur[c], 1);
      ckv[pos] = v;
    }
  }
}

// ---------- K5: per-bucket fine grouping by dst&255 -> rs[], esort ----------
__global__ __launch_bounds__(1024) void k_fine(
    const uint32* __restrict__ ckv, const int* __restrict__ base,
    uint32* __restrict__ esort, int* __restrict__ rs, int N){
  __shared__ int h[256];
  __shared__ int cur[256];
  const int c  = blockIdx.x;
  const int lo = base[c], hi = base[c + 1];
  const int t  = threadIdx.x;
  if (t < 256) h[t] = 0;
  __syncthreads();
  for (int i = lo + t; i < hi; i += 1024)
    atomicAdd(&h[(ckv[i] >> 19) & 255], 1);
  __syncthreads();
  int v = (t < 256) ? h[t] : 0;
  __syncthreads();
  for (int off = 1; off < 256; off <<= 1){
    int xv = 0;
    if (t < 256 && t >= off) xv = h[t - off];
    __syncthreads();
    if (t < 256) h[t] += xv;
    __syncthreads();
  }
  if (t < 256){
    int excl = h[t] - v;
    cur[t] = lo + excl;
    int idx = c * 256 + t;
    if (idx <= N) rs[idx] = lo + excl;
  }
  __syncthreads();
  for (int i = lo + t; i < hi; i += 1024){
    uint32 v2 = ckv[i];
    int pos = atomicAdd(&cur[(v2 >> 19) & 255], 1);
    esort[pos] = v2;
  }
}

// ---------- K6: aggregation: 8-deep gather unroll, nt stores ----------
#define ACCUM(P, V) \
  switch (((P) >> 16) & 7){ \
    case 0: acc[0].x+=bfl(V); acc[0].y+=bfh(V); break; case 1: acc[1].x+=bfl(V); acc[1].y+=bfh(V); break; \
    case 2: acc[2].x+=bfl(V); acc[2].y+=bfh(V); break; case 3: acc[3].x+=bfl(V); acc[3].y+=bfh(V); break; \
    case 4: acc[4].x+=bfl(V); acc[4].y+=bfh(V); break; case 5: acc[5].x+=bfl(V); acc[5].y+=bfh(V); break; \
    case 6: acc[6].x+=bfl(V); acc[6].y+=bfh(V); break; case 7: acc[7].x+=bfl(V); acc[7].y+=bfh(V); break; \
  }

__global__ __launch_bounds__(256) void k_agg(const uint32* __restrict__ xb,
                                             const int* __restrict__ rs,
                                             const uint32* __restrict__ esort,
                                             uint32* __restrict__ hcat,
                                             float* __restrict__ invdeg, int N){
  int wave = threadIdx.x >> 6;
  int lane = threadIdx.x & 63;
  int n = blockIdx.x * 4 + wave;
  if (n >= N) return;
  int beg = rs[n], end = rs[n + 1];
  float2 acc[NREL];
  #pragma unroll
  for (int r = 0; r < NREL; ++r){ acc[r].x = 0.f; acc[r].y = 0.f; }

  int i = beg;
  for (; i + 7 < end; i += 8){
    uint32 p0 = esort[i],   p1 = esort[i+1], p2 = esort[i+2], p3 = esort[i+3];
    uint32 p4 = esort[i+4], p5 = esort[i+5], p6 = esort[i+6], p7 = esort[i+7];
    uint32 v0 = xb[(size_t)(p0 & 0xFFFF) * 64 + lane];
    uint32 v1 = xb[(size_t)(p1 & 0xFFFF) * 64 + lane];
    uint32 v2 = xb[(size_t)(p2 & 0xFFFF) * 64 + lane];
    uint32 v3 = xb[(size_t)(p3 & 0xFFFF) * 64 + lane];
    uint32 v4 = xb[(size_t)(p4 & 0xFFFF) * 64 + lane];
    uint32 v5 = xb[(size_t)(p5 & 0xFFFF) * 64 + lane];
    uint32 v6 = xb[(size_t)(p6 & 0xFFFF) * 64 + lane];
    uint32 v7 = xb[(size_t)(p7 & 0xFFFF) * 64 + lane];
    ACCUM(p0, v0) ACCUM(p1, v1) ACCUM(p2, v2) ACCUM(p3, v3)
    ACCUM(p4, v4) ACCUM(p5, v5) ACCUM(p6, v6) ACCUM(p7, v7)
  }
  for (; i + 3 < end; i += 4){
    uint32 p0 = esort[i], p1 = esort[i+1], p2 = esort[i+2], p3 = esort[i+3];
    uint32 v0 = xb[(size_t)(p0 & 0xFFFF) * 64 + lane];
    uint32 v1 = xb[(size_t)(p1 & 0xFFFF) * 64 + lane];
    uint32 v2 = xb[(size_t)(p2 & 0xFFFF) * 64 + lane];
    uint32 v3 = xb[(size_t)(p3 & 0xFFFF) * 64 + lane];
    ACCUM(p0, v0) ACCUM(p1, v1) ACCUM(p2, v2) ACCUM(p3, v3)
  }
  for (; i < end; ++i){
    uint32 p = esort[i];
    uint32 v = xb[(size_t)(p & 0xFFFF) * 64 + lane];
    ACCUM(p, v)
  }

  size_t b2 = (size_t)n * (KCAT / 2);
  #pragma unroll
  for (int r = 0; r < NREL; ++r){
    __hip_bfloat162 pk = __float22bfloat162_rn(make_float2(acc[r].x, acc[r].y));
    __builtin_nontemporal_store(*reinterpret_cast<uint32*>(&pk), &hcat[b2 + r * 64 + lane]);
  }
  __builtin_nontemporal_store(xb[(size_t)n * 64 + lane], &hcat[b2 + 512 + lane]);
  if (lane == 0){
    int d = end - beg;
    invdeg[n] = 1.0f / (float)(d > 0 ? d : 1);
  }
}

// ---------- K7: GEMM, A via gl_lds dbuf, B direct-to-reg prefetch ----------
__global__ __launch_bounds__(256) void k_gemm2(
    const short* __restrict__ acat,   // [Npad][1152] bf16
    const short* __restrict__ wb,     // [128][1152]  bf16
    const float* __restrict__ invdeg,
    float* __restrict__ out, int N)
{
  __shared__ char smem[16384];        // As0 8K | As1 8K
  char* As0 = smem;
  char* As1 = smem + 8192;

  const int tid  = threadIdx.x;
  const int lane = tid & 63;
  const int wid  = tid >> 6;
  const int wr   = wid >> 1;
  const int wc   = wid & 1;
  const int n0   = blockIdx.x * 64;
  const int lr   = lane & 15;
  const int lq   = lane >> 4;

  f32x4 acc[2][4];
  #pragma unroll
  for (int m = 0; m < 2; ++m)
    #pragma unroll
    for (int p = 0; p < 4; ++p)
      acc[m][p] = (f32x4){0.f, 0.f, 0.f, 0.f};

  const int srow = tid >> 3;
  const int scs  = tid & 7;

  auto STAGE_A = [&](char* Ab, int ks){
    const short* ab = acat + (size_t)n0 * KCAT + ks * 64;
    #pragma unroll
    for (int q = 0; q < 2; ++q){
      int row = q * 32 + srow;
      const short* src = ab + (size_t)row * KCAT + ((scs ^ (row & 7)) << 3);
      gload_lds16(src, Ab + q * 4096 + (wid << 10));
    }
  };

  // B frag pointers: row j = wc*64 + p*16 + lr, element ks*64 + kk*32 + lq*8
  const short* wbase = wb + (size_t)(wc * 64 + lr) * KCAT + lq * 8;

  auto LOAD_B = [&](bf16x8 (&b)[2][4], int ks){
    #pragma unroll
    for (int kk = 0; kk < 2; ++kk)
      #pragma unroll
      for (int p = 0; p < 4; ++p)
        b[kk][p] = *(const bf16x8*)(wbase + (size_t)p * 16 * KCAT + ks * 64 + kk * 32);
  };

  auto COMPUTE = [&](const char* Ab, const bf16x8 (&b)[2][4]){
    bf16x8 a[2][2];
    #pragma unroll
    for (int kk = 0; kk < 2; ++kk)
      #pragma unroll
      for (int m = 0; m < 2; ++m){
        int row = wr * 32 + m * 16 + lr;
        int c   = kk * 4 + lq;
        a[kk][m] = *(const bf16x8*)(Ab + row * 128 + ((c ^ (row & 7)) << 4));
      }
    #pragma unroll
    for (int kk = 0; kk < 2; ++kk)
      #pragma unroll
      for (int m = 0; m < 2; ++m)
        #pragma unroll
        for (int p = 0; p < 4; ++p)
          acc[m][p] = __builtin_amdgcn_mfma_f32_16x16x32_bf16(a[kk][m], b[kk][p], acc[m][p], 0, 0, 0);
  };

  bf16x8 bA[2][4], bB[2][4];
  LOAD_B(bA, 0);
  STAGE_A(As0, 0);
  __syncthreads();
  for (int ks = 0; ks < 18; ks += 2){
    STAGE_A(As1, ks + 1);
    LOAD_B(bB, ks + 1);
    COMPUTE(As0, bA);
    __syncthreads();
    if (ks + 2 < 18){
      STAGE_A(As0, ks + 2);
      LOAD_B(bA, ks + 2);
    }
    COMPUTE(As1, bB);
    __syncthreads();
  }

  #pragma unroll
  for (int m = 0; m < 2; ++m){
    int rbase = n0 + wr * 32 + m * 16 + lq * 4;
    #pragma unroll
    for (int v = 0; v < 4; ++v){
      int ro = rbase + v;
      if (ro < N){
        float inv = invdeg[ro];
        #pragma unroll
        for (int p = 0; p < 4; ++p)
          __builtin_nontemporal_store(acc[m][p][v] * inv,
              &out[(((size_t)ro) << 7) + wc * 64 + p * 16 + lr]);
      }
    }
  }
}

extern "C" void kernel_launch(void* const* d_in, const int* in_sizes, int n_in,
                              void* d_out, int out_size, void* d_ws, size_t ws_size,
                              hipStream_t stream){
  const float* x  = (const float*)d_in[0];
  const int*   ei = (const int*)d_in[1];
  const int*   et = (const int*)d_in[2];
  const float* W  = (const float*)d_in[4];
  const float* W0 = (const float*)d_in[5];
  float* out = (float*)d_out;

  const int N = in_sizes[0] / NDIM;   // 50000
  const int E = in_sizes[2];          // 800000
  const int Npad = N + 64;
  const int nblkE = (E + EPB - 1) / EPB;   // 196

  char* ws = (char*)d_ws;
  size_t off = 0;
  auto alloc = [&](size_t bytes)->size_t{
    size_t p = off; off = (off + bytes + 255) & ~(size_t)255; return p;
  };
  size_t o_flag = alloc(4);
  size_t o_kv   = alloc((size_t)E * 4);
  size_t o_ct   = alloc((size_t)E);
  size_t o_ckv  = alloc((size_t)E * 4);
  size_t o_es   = alloc((size_t)E * 4);
  size_t o_cc   = alloc(COARSE * 4);
  size_t o_base = alloc((COARSE + 2) * 4);
  size_t o_br   = alloc((size_t)nblkE * COARSE * 4);
  size_t o_rs   = alloc((size_t)(N + 1) * 4);
  size_t o_inv  = alloc((size_t)N * 4);
  size_t o_h    = alloc((size_t)Npad * KCAT * 2);
  size_t o_wb   = alloc((size_t)NDIM * KCAT * 2);
  size_t o_xb   = alloc((size_t)N * NDIM * 2);
  (void)ws_size;

  int*  flag   = (int*)(ws + o_flag);
  uint32* kv   = (uint32*)(ws + o_kv);
  unsigned char* ctmp = (unsigned char*)(ws + o_ct);
  uint32* ckv  = (uint32*)(ws + o_ckv);
  uint32* esort= (uint32*)(ws + o_es);
  int*  ccnt   = (int*)(ws + o_cc);
  int*  base   = (int*)(ws + o_base);
  int*  bres   = (int*)(ws + o_br);
  int*  rs     = (int*)(ws + o_rs);
  float* invdeg= (float*)(ws + o_inv);
  uint32* hcat = (uint32*)(ws + o_h);
  short* acat  = (short*)(ws + o_h);
  short* Wbs   = (short*)(ws + o_wb);
  uint32* xb   = (uint32*)(ws + o_xb);

  const int n4      = N * NDIM / 4;
  const int xblocks = (n4 + 255) / 256;             // 6250
  const int wblocks = (NDIM * KCAT + 255) / 256;    // 576

  k_prep<<<xblocks + wblocks + 1, 256, 0, stream>>>(
      x, xb, n4, xblocks, W, W0, Wbs, wblocks, ei, flag, ccnt);
  k_hist<<<nblkE, 1024, 0, stream>>>(ei, et, flag, kv, ctmp, ccnt, bres, E);
  k_base<<<1, 256, 0, stream>>>(ccnt, base);
  k_cscatter<<<nblkE, 1024, 0, stream>>>(kv, ctmp, base, bres, ckv, E);
  k_fine<<<COARSE, 1024, 0, stream>>>(ckv, base, esort, rs, N);
  k_agg<<<(N + 3) / 4, 256, 0, stream>>>(xb, rs, esort, hcat, invdeg, N);
  k_gemm2<<<(N + 63) / 64, 256, 0, stream>>>(acat, Wbs, invdeg, out, N);
}

// Round 11
// 117.020 us; speedup vs baseline: 1.3899x; 1.3899x over previous
//
#include <hip/hip_runtime.h>
#include <hip/hip_bf16.h>
#include <cstdint>
#include <cstddef>

// RGCN layer: out = (x@W0 + sum_r h_r@W[r]) / max(deg,1)
// Round-11: round-9 proven structure; gemm B re-staged via LDS (round-10's
// direct-B reverted: latency-bound, occ 21%). Self-slot eliminated: hcat is
// 8 slots (stride 1024); gemm K-steps 16-17 stage A directly from xb.

#define NDIM 128
#define NREL 8
#define KR   1024        // 8*128 (hcat row)
#define KCAT 1152        // 9*128 (GEMM K)
#define COARSE 196       // dst>>8 buckets
#define EPB 4096         // edges per hist/cscatter block

typedef __attribute__((ext_vector_type(8))) short bf16x8;
typedef __attribute__((ext_vector_type(4))) float f32x4;
typedef unsigned int uint32;

__device__ __forceinline__ short f2bf(float f){
  __hip_bfloat16 h = __float2bfloat16(f);
  return *reinterpret_cast<short*>(&h);
}
__device__ __forceinline__ float bfl(uint32 v){ return __uint_as_float(v << 16); }
__device__ __forceinline__ float bfh(uint32 v){ return __uint_as_float(v & 0xFFFF0000u); }

__device__ __forceinline__ void gload_lds16(const void* g, void* l){
  __builtin_amdgcn_global_load_lds(
      (const __attribute__((address_space(1))) unsigned int*)g,
      (__attribute__((address_space(3))) unsigned int*)l, 16, 0, 0);
}

// ---------- K1: casts + zero coarse_cnt + detect ----------
__global__ void k_prep(const float* __restrict__ x, uint32* __restrict__ xb, int n4, int xblocks,
                       const float* __restrict__ W, const float* __restrict__ W0,
                       short* __restrict__ Wb, int wblocks,
                       const int* __restrict__ ei, int* flag, int* coarse_cnt){
  int b = blockIdx.x;
  if (b < xblocks){
    int i = b * 256 + threadIdx.x;
    if (i >= n4) return;
    float4 f = ((const float4*)x)[i];
    uint32 lo = ((uint32)(unsigned short)f2bf(f.x)) | (((uint32)(unsigned short)f2bf(f.y)) << 16);
    uint32 hi = ((uint32)(unsigned short)f2bf(f.z)) | (((uint32)(unsigned short)f2bf(f.w)) << 16);
    ((uint2*)xb)[i] = make_uint2(lo, hi);
  } else if (b < xblocks + wblocks){
    int i = (b - xblocks) * 256 + threadIdx.x;
    if (i >= NDIM * KCAT) return;
    int j  = i / KCAT;
    int t  = i - j * KCAT;
    int r  = t >> 7;
    int kd = t & 127;
    float v = (r < NREL) ? W[(((size_t)r * NDIM + kd) << 7) + j] : W0[((size_t)kd << 7) + j];
    Wb[i] = f2bf(v);
  } else {
    if (threadIdx.x < COARSE) coarse_cnt[threadIdx.x] = 0;
    if (threadIdx.x < 64){
      int v = ei[2 * threadIdx.x + 1];
      unsigned long long m = __ballot(v == 0);
      if (threadIdx.x == 0) flag[0] = (m == ~0ull) ? 1 : 0;
    }
  }
}

// ---------- K2: decode + pack + coarse LDS hist + block reservations ----------
__global__ __launch_bounds__(1024) void k_hist(
    const int* __restrict__ ei, const int* __restrict__ et, const int* __restrict__ flag,
    uint32* __restrict__ kv, unsigned char* __restrict__ ctmp,
    int* __restrict__ coarse_cnt, int* __restrict__ blockRes, int E){
  __shared__ int h[COARSE];
  const int b = blockIdx.x;
  for (int i = threadIdx.x; i < COARSE; i += 1024) h[i] = 0;
  __syncthreads();
  const int is64 = flag[0];
  const int e0 = b * EPB;
  for (int i = threadIdx.x; i < EPB; i += 1024){
    int e = e0 + i;
    if (e < E){
      int s, d, t;
      if (is64){ s = ei[2*e]; d = ei[2*(E + e)]; t = et[2*e]; }
      else     { s = ei[e];   d = ei[E + e];     t = et[e];   }
      int c = d >> 8;
      kv[e]   = (uint32)s | ((uint32)t << 16) | ((uint32)(d & 255) << 19);
      ctmp[e] = (unsigned char)c;
      atomicAdd(&h[c], 1);
    }
  }
  __syncthreads();
  for (int c = threadIdx.x; c < COARSE; c += 1024){
    int cnt = h[c];
    int res = 0;
    if (cnt > 0) res = atomicAdd(&coarse_cnt[c], cnt);
    blockRes[b * COARSE + c] = res;
  }
}

// ---------- K3: scan coarse counts -> base ----------
__global__ void k_base(const int* __restrict__ coarse_cnt, int* __restrict__ base){
  __shared__ int sm[256];
  int t = threadIdx.x;
  int v = (t < COARSE) ? coarse_cnt[t] : 0;
  sm[t] = v; __syncthreads();
  #pragma unroll
  for (int off = 1; off < 256; off <<= 1){
    int xv = 0; if (t >= off) xv = sm[t - off];
    __syncthreads(); sm[t] += xv; __syncthreads();
  }
  if (t <= COARSE) base[t] = sm[t] - v;
}

// ---------- K4: coarse scatter (LDS cursors) ----------
__global__ __launch_bounds__(1024) void k_cscatter(
    const uint32* __restrict__ kv, const unsigned char* __restrict__ ctmp,
    const int* __restrict__ base, const int* __restrict__ blockRes,
    uint32* __restrict__ ckv, int E){
  __shared__ int cur[COARSE];
  const int b = blockIdx.x;
  for (int c = threadIdx.x; c < COARSE; c += 1024)
    cur[c] = base[c] + blockRes[b * COARSE + c];
  __syncthreads();
  const int e0 = b * EPB;
  for (int i = threadIdx.x; i < EPB; i += 1024){
    int e = e0 + i;
    if (e < E){
      uint32 v = kv[e];
      int c = ctmp[e];
      int pos = atomicAdd(&cur[c], 1);
      ckv[pos] = v;
    }
  }
}

// ---------- K5: per-bucket fine grouping by dst&255 -> rs[], esort ----------
__global__ __launch_bounds__(1024) void k_fine(
    const uint32* __restrict__ ckv, const int* __restrict__ base,
    uint32* __restrict__ esort, int* __restrict__ rs, int N){
  __shared__ int h[256];
  __shared__ int cur[256];
  const int c  = blockIdx.x;
  const int lo = base[c], hi = base[c + 1];
  const int t  = threadIdx.x;
  if (t < 256) h[t] = 0;
  __syncthreads();
  for (int i = lo + t; i < hi; i += 1024)
    atomicAdd(&h[(ckv[i] >> 19) & 255], 1);
  __syncthreads();
  int v = (t < 256) ? h[t] : 0;
  __syncthreads();
  for (int off = 1; off < 256; off <<= 1){
    int xv = 0;
    if (t < 256 && t >= off) xv = h[t - off];
    __syncthreads();
    if (t < 256) h[t] += xv;
    __syncthreads();
  }
  if (t < 256){
    int excl = h[t] - v;
    cur[t] = lo + excl;
    int idx = c * 256 + t;
    if (idx <= N) rs[idx] = lo + excl;
  }
  __syncthreads();
  for (int i = lo + t; i < hi; i += 1024){
    uint32 v2 = ckv[i];
    int pos = atomicAdd(&cur[(v2 >> 19) & 255], 1);
    esort[pos] = v2;
  }
}

// ---------- K6: aggregation: 8-deep unroll, nt stores, 8-slot rows ----------
#define ACCUM(P, V) \
  switch (((P) >> 16) & 7){ \
    case 0: acc[0].x+=bfl(V); acc[0].y+=bfh(V); break; case 1: acc[1].x+=bfl(V); acc[1].y+=bfh(V); break; \
    case 2: acc[2].x+=bfl(V); acc[2].y+=bfh(V); break; case 3: acc[3].x+=bfl(V); acc[3].y+=bfh(V); break; \
    case 4: acc[4].x+=bfl(V); acc[4].y+=bfh(V); break; case 5: acc[5].x+=bfl(V); acc[5].y+=bfh(V); break; \
    case 6: acc[6].x+=bfl(V); acc[6].y+=bfh(V); break; case 7: acc[7].x+=bfl(V); acc[7].y+=bfh(V); break; \
  }

__global__ __launch_bounds__(256) void k_agg(const uint32* __restrict__ xb,
                                             const int* __restrict__ rs,
                                             const uint32* __restrict__ esort,
                                             uint32* __restrict__ hcat,
                                             float* __restrict__ invdeg, int N){
  int wave = threadIdx.x >> 6;
  int lane = threadIdx.x & 63;
  int n = blockIdx.x * 4 + wave;
  if (n >= N) return;
  int beg = rs[n], end = rs[n + 1];
  float2 acc[NREL];
  #pragma unroll
  for (int r = 0; r < NREL; ++r){ acc[r].x = 0.f; acc[r].y = 0.f; }

  int i = beg;
  for (; i + 7 < end; i += 8){
    uint32 p0 = esort[i],   p1 = esort[i+1], p2 = esort[i+2], p3 = esort[i+3];
    uint32 p4 = esort[i+4], p5 = esort[i+5], p6 = esort[i+6], p7 = esort[i+7];
    uint32 v0 = xb[(size_t)(p0 & 0xFFFF) * 64 + lane];
    uint32 v1 = xb[(size_t)(p1 & 0xFFFF) * 64 + lane];
    uint32 v2 = xb[(size_t)(p2 & 0xFFFF) * 64 + lane];
    uint32 v3 = xb[(size_t)(p3 & 0xFFFF) * 64 + lane];
    uint32 v4 = xb[(size_t)(p4 & 0xFFFF) * 64 + lane];
    uint32 v5 = xb[(size_t)(p5 & 0xFFFF) * 64 + lane];
    uint32 v6 = xb[(size_t)(p6 & 0xFFFF) * 64 + lane];
    uint32 v7 = xb[(size_t)(p7 & 0xFFFF) * 64 + lane];
    ACCUM(p0, v0) ACCUM(p1, v1) ACCUM(p2, v2) ACCUM(p3, v3)
    ACCUM(p4, v4) ACCUM(p5, v5) ACCUM(p6, v6) ACCUM(p7, v7)
  }
  for (; i + 3 < end; i += 4){
    uint32 p0 = esort[i], p1 = esort[i+1], p2 = esort[i+2], p3 = esort[i+3];
    uint32 v0 = xb[(size_t)(p0 & 0xFFFF) * 64 + lane];
    uint32 v1 = xb[(size_t)(p1 & 0xFFFF) * 64 + lane];
    uint32 v2 = xb[(size_t)(p2 & 0xFFFF) * 64 + lane];
    uint32 v3 = xb[(size_t)(p3 & 0xFFFF) * 64 + lane];
    ACCUM(p0, v0) ACCUM(p1, v1) ACCUM(p2, v2) ACCUM(p3, v3)
  }
  for (; i < end; ++i){
    uint32 p = esort[i];
    uint32 v = xb[(size_t)(p & 0xFFFF) * 64 + lane];
    ACCUM(p, v)
  }

  size_t b2 = (size_t)n * (KR / 2);
  #pragma unroll
  for (int r = 0; r < NREL; ++r){
    __hip_bfloat162 pk = __float22bfloat162_rn(make_float2(acc[r].x, acc[r].y));
    __builtin_nontemporal_store(*reinterpret_cast<uint32*>(&pk), &hcat[b2 + r * 64 + lane]);
  }
  if (lane == 0){
    int d = end - beg;
    invdeg[n] = 1.0f / (float)(d > 0 ? d : 1);
  }
}

// ---------- K7: GEMM (round-9 staged A+B; A ks 16-17 from xb) ----------
__global__ __launch_bounds__(256) void k_gemm2(
    const short* __restrict__ acat,   // [Npad][1024] bf16 (8 rel slots)
    const short* __restrict__ xbs,    // [Npad][128]  bf16 (self rows)
    const short* __restrict__ wb,     // [128][1152]  bf16
    const float* __restrict__ invdeg,
    float* __restrict__ out, int N)
{
  __shared__ char smem[49152];
  char* As0 = smem;
  char* As1 = smem + 8192;
  char* Bs0 = smem + 16384;
  char* Bs1 = smem + 32768;

  const int tid  = threadIdx.x;
  const int lane = tid & 63;
  const int wid  = tid >> 6;
  const int wr   = wid >> 1;
  const int wc   = wid & 1;
  const int n0   = blockIdx.x * 64;
  const int lr   = lane & 15;
  const int lq   = lane >> 4;

  f32x4 acc[2][4];
  #pragma unroll
  for (int m = 0; m < 2; ++m)
    #pragma unroll
    for (int p = 0; p < 4; ++p)
      acc[m][p] = (f32x4){0.f, 0.f, 0.f, 0.f};

  const int srow = tid >> 3;
  const int scs  = tid & 7;

  auto STAGE = [&](char* Ab, char* Bb, int ks){
    const short* ab;
    size_t rstride;
    if (ks < 16){ ab = acat + (size_t)n0 * KR + ks * 64;          rstride = KR;  }
    else        { ab = xbs  + (size_t)n0 * 128 + (ks - 16) * 64;  rstride = 128; }
    #pragma unroll
    for (int q = 0; q < 2; ++q){
      int row = q * 32 + srow;
      const short* src = ab + (size_t)row * rstride + ((scs ^ (row & 7)) << 3);
      gload_lds16(src, Ab + q * 4096 + (wid << 10));
    }
    const short* bb = wb + ks * 64;
    #pragma unroll
    for (int q = 0; q < 4; ++q){
      int j = q * 32 + srow;
      const short* src = bb + (size_t)j * KCAT + ((scs ^ (j & 7)) << 3);
      gload_lds16(src, Bb + q * 4096 + (wid << 10));
    }
  };

  auto COMPUTE = [&](const char* Ab, const char* Bb){
    bf16x8 a[2][2], b[2][4];
    #pragma unroll
    for (int kk = 0; kk < 2; ++kk){
      #pragma unroll
      for (int m = 0; m < 2; ++m){
        int row = wr * 32 + m * 16 + lr;
        int c   = kk * 4 + lq;
        a[kk][m] = *(const bf16x8*)(Ab + row * 128 + ((c ^ (row & 7)) << 4));
      }
      #pragma unroll
      for (int p = 0; p < 4; ++p){
        int j = wc * 64 + p * 16 + lr;
        int c = kk * 4 + lq;
        b[kk][p] = *(const bf16x8*)(Bb + j * 128 + ((c ^ (j & 7)) << 4));
      }
    }
    #pragma unroll
    for (int kk = 0; kk < 2; ++kk)
      #pragma unroll
      for (int m = 0; m < 2; ++m)
        #pragma unroll
        for (int p = 0; p < 4; ++p)
          acc[m][p] = __builtin_amdgcn_mfma_f32_16x16x32_bf16(a[kk][m], b[kk][p], acc[m][p], 0, 0, 0);
  };

  STAGE(As0, Bs0, 0);
  __syncthreads();
  for (int ks = 0; ks < 18; ks += 2){
    STAGE(As1, Bs1, ks + 1);
    COMPUTE(As0, Bs0);
    __syncthreads();
    if (ks + 2 < 18) STAGE(As0, Bs0, ks + 2);
    COMPUTE(As1, Bs1);
    __syncthreads();
  }

  #pragma unroll
  for (int m = 0; m < 2; ++m){
    int rbase = n0 + wr * 32 + m * 16 + lq * 4;
    #pragma unroll
    for (int v = 0; v < 4; ++v){
      int ro = rbase + v;
      if (ro < N){
        float inv = invdeg[ro];
        #pragma unroll
        for (int p = 0; p < 4; ++p)
          __builtin_nontemporal_store(acc[m][p][v] * inv,
              &out[(((size_t)ro) << 7) + wc * 64 + p * 16 + lr]);
      }
    }
  }
}

extern "C" void kernel_launch(void* const* d_in, const int* in_sizes, int n_in,
                              void* d_out, int out_size, void* d_ws, size_t ws_size,
                              hipStream_t stream){
  const float* x  = (const float*)d_in[0];
  const int*   ei = (const int*)d_in[1];
  const int*   et = (const int*)d_in[2];
  const float* W  = (const float*)d_in[4];
  const float* W0 = (const float*)d_in[5];
  float* out = (float*)d_out;

  const int N = in_sizes[0] / NDIM;   // 50000
  const int E = in_sizes[2];          // 800000
  const int Npad = N + 64;
  const int nblkE = (E + EPB - 1) / EPB;   // 196

  char* ws = (char*)d_ws;
  size_t off = 0;
  auto alloc = [&](size_t bytes)->size_t{
    size_t p = off; off = (off + bytes + 255) & ~(size_t)255; return p;
  };
  size_t o_flag = alloc(4);
  size_t o_kv   = alloc((size_t)E * 4);
  size_t o_ct   = alloc((size_t)E);
  size_t o_ckv  = alloc((size_t)E * 4);
  size_t o_es   = alloc((size_t)E * 4);
  size_t o_cc   = alloc(COARSE * 4);
  size_t o_base = alloc((COARSE + 2) * 4);
  size_t o_br   = alloc((size_t)nblkE * COARSE * 4);
  size_t o_rs   = alloc((size_t)(N + 1) * 4);
  size_t o_inv  = alloc((size_t)N * 4);
  size_t o_h    = alloc((size_t)Npad * KR * 2);
  size_t o_wb   = alloc((size_t)NDIM * KCAT * 2);
  size_t o_xb   = alloc((size_t)Npad * NDIM * 2);   // padded for GEMM tail
  (void)ws_size;

  int*  flag   = (int*)(ws + o_flag);
  uint32* kv   = (uint32*)(ws + o_kv);
  unsigned char* ctmp = (unsigned char*)(ws + o_ct);
  uint32* ckv  = (uint32*)(ws + o_ckv);
  uint32* esort= (uint32*)(ws + o_es);
  int*  ccnt   = (int*)(ws + o_cc);
  int*  base   = (int*)(ws + o_base);
  int*  bres   = (int*)(ws + o_br);
  int*  rs     = (int*)(ws + o_rs);
  float* invdeg= (float*)(ws + o_inv);
  uint32* hcat = (uint32*)(ws + o_h);
  short* acat  = (short*)(ws + o_h);
  short* Wbs   = (short*)(ws + o_wb);
  uint32* xb   = (uint32*)(ws + o_xb);
  short* xbs   = (short*)(ws + o_xb);

  const int n4      = N * NDIM / 4;
  const int xblocks = (n4 + 255) / 256;             // 6250
  const int wblocks = (NDIM * KCAT + 255) / 256;    // 576

  k_prep<<<xblocks + wblocks + 1, 256, 0, stream>>>(
      x, xb, n4, xblocks, W, W0, Wbs, wblocks, ei, flag, ccnt);
  k_hist<<<nblkE, 1024, 0, stream>>>(ei, et, flag, kv, ctmp, ccnt, bres, E);
  k_base<<<1, 256, 0, stream>>>(ccnt, base);
  k_cscatter<<<nblkE, 1024, 0, stream>>>(kv, ctmp, base, bres, ckv, E);
  k_fine<<<COARSE, 1024, 0, stream>>>(ckv, base, esort, rs, N);
  k_agg<<<(N + 3) / 4, 256, 0, stream>>>(xb, rs, esort, hcat, invdeg, N);
  k_gemm2<<<(N + 63) / 64, 256, 0, stream>>>(acat, xbs, Wbs, invdeg, out, N);
}

// Round 12
// 105.375 us; speedup vs baseline: 1.5435x; 1.1105x over previous
//
#include <hip/hip_runtime.h>
#include <hip/hip_bf16.h>
#include <cstdint>
#include <cstddef>

// RGCN layer: out = (x@W0 + sum_r h_r@W[r]) / max(deg,1)
// Round-12: gemm tile BM=128 (m93-proven shape): 512 thr / 8 waves, 64 KB LDS,
// 2 blocks/CU; staging drops to 4 loads/thread/step, B-stage traffic halves.
// agg + preprocessing identical to round 11 (best-known).

#define NDIM 128
#define NREL 8
#define KR   1024        // 8*128 (hcat row)
#define KCAT 1152        // 9*128 (GEMM K)
#define COARSE 196       // dst>>8 buckets
#define EPB 4096         // edges per hist/cscatter block

typedef __attribute__((ext_vector_type(8))) short bf16x8;
typedef __attribute__((ext_vector_type(4))) float f32x4;
typedef unsigned int uint32;

__device__ __forceinline__ short f2bf(float f){
  __hip_bfloat16 h = __float2bfloat16(f);
  return *reinterpret_cast<short*>(&h);
}
__device__ __forceinline__ float bfl(uint32 v){ return __uint_as_float(v << 16); }
__device__ __forceinline__ float bfh(uint32 v){ return __uint_as_float(v & 0xFFFF0000u); }

__device__ __forceinline__ void gload_lds16(const void* g, void* l){
  __builtin_amdgcn_global_load_lds(
      (const __attribute__((address_space(1))) unsigned int*)g,
      (__attribute__((address_space(3))) unsigned int*)l, 16, 0, 0);
}

// ---------- K1: casts + zero coarse_cnt + detect ----------
__global__ void k_prep(const float* __restrict__ x, uint32* __restrict__ xb, int n4, int xblocks,
                       const float* __restrict__ W, const float* __restrict__ W0,
                       short* __restrict__ Wb, int wblocks,
                       const int* __restrict__ ei, int* flag, int* coarse_cnt){
  int b = blockIdx.x;
  if (b < xblocks){
    int i = b * 256 + threadIdx.x;
    if (i >= n4) return;
    float4 f = ((const float4*)x)[i];
    uint32 lo = ((uint32)(unsigned short)f2bf(f.x)) | (((uint32)(unsigned short)f2bf(f.y)) << 16);
    uint32 hi = ((uint32)(unsigned short)f2bf(f.z)) | (((uint32)(unsigned short)f2bf(f.w)) << 16);
    ((uint2*)xb)[i] = make_uint2(lo, hi);
  } else if (b < xblocks + wblocks){
    int i = (b - xblocks) * 256 + threadIdx.x;
    if (i >= NDIM * KCAT) return;
    int j  = i / KCAT;
    int t  = i - j * KCAT;
    int r  = t >> 7;
    int kd = t & 127;
    float v = (r < NREL) ? W[(((size_t)r * NDIM + kd) << 7) + j] : W0[((size_t)kd << 7) + j];
    Wb[i] = f2bf(v);
  } else {
    if (threadIdx.x < COARSE) coarse_cnt[threadIdx.x] = 0;
    if (threadIdx.x < 64){
      int v = ei[2 * threadIdx.x + 1];
      unsigned long long m = __ballot(v == 0);
      if (threadIdx.x == 0) flag[0] = (m == ~0ull) ? 1 : 0;
    }
  }
}

// ---------- K2: decode + pack + coarse LDS hist + block reservations ----------
__global__ __launch_bounds__(1024) void k_hist(
    const int* __restrict__ ei, const int* __restrict__ et, const int* __restrict__ flag,
    uint32* __restrict__ kv, unsigned char* __restrict__ ctmp,
    int* __restrict__ coarse_cnt, int* __restrict__ blockRes, int E){
  __shared__ int h[COARSE];
  const int b = blockIdx.x;
  for (int i = threadIdx.x; i < COARSE; i += 1024) h[i] = 0;
  __syncthreads();
  const int is64 = flag[0];
  const int e0 = b * EPB;
  for (int i = threadIdx.x; i < EPB; i += 1024){
    int e = e0 + i;
    if (e < E){
      int s, d, t;
      if (is64){ s = ei[2*e]; d = ei[2*(E + e)]; t = et[2*e]; }
      else     { s = ei[e];   d = ei[E + e];     t = et[e];   }
      int c = d >> 8;
      kv[e]   = (uint32)s | ((uint32)t << 16) | ((uint32)(d & 255) << 19);
      ctmp[e] = (unsigned char)c;
      atomicAdd(&h[c], 1);
    }
  }
  __syncthreads();
  for (int c = threadIdx.x; c < COARSE; c += 1024){
    int cnt = h[c];
    int res = 0;
    if (cnt > 0) res = atomicAdd(&coarse_cnt[c], cnt);
    blockRes[b * COARSE + c] = res;
  }
}

// ---------- K3: scan coarse counts -> base ----------
__global__ void k_base(const int* __restrict__ coarse_cnt, int* __restrict__ base){
  __shared__ int sm[256];
  int t = threadIdx.x;
  int v = (t < COARSE) ? coarse_cnt[t] : 0;
  sm[t] = v; __syncthreads();
  #pragma unroll
  for (int off = 1; off < 256; off <<= 1){
    int xv = 0; if (t >= off) xv = sm[t - off];
    __syncthreads(); sm[t] += xv; __syncthreads();
  }
  if (t <= COARSE) base[t] = sm[t] - v;
}

// ---------- K4: coarse scatter (LDS cursors) ----------
__global__ __launch_bounds__(1024) void k_cscatter(
    const uint32* __restrict__ kv, const unsigned char* __restrict__ ctmp,
    const int* __restrict__ base, const int* __restrict__ blockRes,
    uint32* __restrict__ ckv, int E){
  __shared__ int cur[COARSE];
  const int b = blockIdx.x;
  for (int c = threadIdx.x; c < COARSE; c += 1024)
    cur[c] = base[c] + blockRes[b * COARSE + c];
  __syncthreads();
  const int e0 = b * EPB;
  for (int i = threadIdx.x; i < EPB; i += 1024){
    int e = e0 + i;
    if (e < E){
      uint32 v = kv[e];
      int c = ctmp[e];
      int pos = atomicAdd(&cur[c], 1);
      ckv[pos] = v;
    }
  }
}

// ---------- K5: per-bucket fine grouping by dst&255 -> rs[], esort ----------
__global__ __launch_bounds__(1024) void k_fine(
    const uint32* __restrict__ ckv, const int* __restrict__ base,
    uint32* __restrict__ esort, int* __restrict__ rs, int N){
  __shared__ int h[256];
  __shared__ int cur[256];
  const int c  = blockIdx.x;
  const int lo = base[c], hi = base[c + 1];
  const int t  = threadIdx.x;
  if (t < 256) h[t] = 0;
  __syncthreads();
  for (int i = lo + t; i < hi; i += 1024)
    atomicAdd(&h[(ckv[i] >> 19) & 255], 1);
  __syncthreads();
  int v = (t < 256) ? h[t] : 0;
  __syncthreads();
  for (int off = 1; off < 256; off <<= 1){
    int xv = 0;
    if (t < 256 && t >= off) xv = h[t - off];
    __syncthreads();
    if (t < 256) h[t] += xv;
    __syncthreads();
  }
  if (t < 256){
    int excl = h[t] - v;
    cur[t] = lo + excl;
    int idx = c * 256 + t;
    if (idx <= N) rs[idx] = lo + excl;
  }
  __syncthreads();
  for (int i = lo + t; i < hi; i += 1024){
    uint32 v2 = ckv[i];
    int pos = atomicAdd(&cur[(v2 >> 19) & 255], 1);
    esort[pos] = v2;
  }
}

// ---------- K6: aggregation: 8-deep unroll, nt stores, 8-slot rows ----------
#define ACCUM(P, V) \
  switch (((P) >> 16) & 7){ \
    case 0: acc[0].x+=bfl(V); acc[0].y+=bfh(V); break; case 1: acc[1].x+=bfl(V); acc[1].y+=bfh(V); break; \
    case 2: acc[2].x+=bfl(V); acc[2].y+=bfh(V); break; case 3: acc[3].x+=bfl(V); acc[3].y+=bfh(V); break; \
    case 4: acc[4].x+=bfl(V); acc[4].y+=bfh(V); break; case 5: acc[5].x+=bfl(V); acc[5].y+=bfh(V); break; \
    case 6: acc[6].x+=bfl(V); acc[6].y+=bfh(V); break; case 7: acc[7].x+=bfl(V); acc[7].y+=bfh(V); break; \
  }

__global__ __launch_bounds__(256) void k_agg(const uint32* __restrict__ xb,
                                             const int* __restrict__ rs,
                                             const uint32* __restrict__ esort,
                                             uint32* __restrict__ hcat,
                                             float* __restrict__ invdeg, int N){
  int wave = threadIdx.x >> 6;
  int lane = threadIdx.x & 63;
  int n = blockIdx.x * 4 + wave;
  if (n >= N) return;
  int beg = rs[n], end = rs[n + 1];
  float2 acc[NREL];
  #pragma unroll
  for (int r = 0; r < NREL; ++r){ acc[r].x = 0.f; acc[r].y = 0.f; }

  int i = beg;
  for (; i + 7 < end; i += 8){
    uint32 p0 = esort[i],   p1 = esort[i+1], p2 = esort[i+2], p3 = esort[i+3];
    uint32 p4 = esort[i+4], p5 = esort[i+5], p6 = esort[i+6], p7 = esort[i+7];
    uint32 v0 = xb[(size_t)(p0 & 0xFFFF) * 64 + lane];
    uint32 v1 = xb[(size_t)(p1 & 0xFFFF) * 64 + lane];
    uint32 v2 = xb[(size_t)(p2 & 0xFFFF) * 64 + lane];
    uint32 v3 = xb[(size_t)(p3 & 0xFFFF) * 64 + lane];
    uint32 v4 = xb[(size_t)(p4 & 0xFFFF) * 64 + lane];
    uint32 v5 = xb[(size_t)(p5 & 0xFFFF) * 64 + lane];
    uint32 v6 = xb[(size_t)(p6 & 0xFFFF) * 64 + lane];
    uint32 v7 = xb[(size_t)(p7 & 0xFFFF) * 64 + lane];
    ACCUM(p0, v0) ACCUM(p1, v1) ACCUM(p2, v2) ACCUM(p3, v3)
    ACCUM(p4, v4) ACCUM(p5, v5) ACCUM(p6, v6) ACCUM(p7, v7)
  }
  for (; i + 3 < end; i += 4){
    uint32 p0 = esort[i], p1 = esort[i+1], p2 = esort[i+2], p3 = esort[i+3];
    uint32 v0 = xb[(size_t)(p0 & 0xFFFF) * 64 + lane];
    uint32 v1 = xb[(size_t)(p1 & 0xFFFF) * 64 + lane];
    uint32 v2 = xb[(size_t)(p2 & 0xFFFF) * 64 + lane];
    uint32 v3 = xb[(size_t)(p3 & 0xFFFF) * 64 + lane];
    ACCUM(p0, v0) ACCUM(p1, v1) ACCUM(p2, v2) ACCUM(p3, v3)
  }
  for (; i < end; ++i){
    uint32 p = esort[i];
    uint32 v = xb[(size_t)(p & 0xFFFF) * 64 + lane];
    ACCUM(p, v)
  }

  size_t b2 = (size_t)n * (KR / 2);
  #pragma unroll
  for (int r = 0; r < NREL; ++r){
    __hip_bfloat162 pk = __float22bfloat162_rn(make_float2(acc[r].x, acc[r].y));
    __builtin_nontemporal_store(*reinterpret_cast<uint32*>(&pk), &hcat[b2 + r * 64 + lane]);
  }
  if (lane == 0){
    int d = end - beg;
    invdeg[n] = 1.0f / (float)(d > 0 ? d : 1);
  }
}

// ---------- K7: GEMM BM=128, 512 thr, 8 waves; A ks 16-17 from xb ----------
__global__ __launch_bounds__(512) void k_gemm2(
    const short* __restrict__ acat,   // [Npad][1024] bf16 (8 rel slots)
    const short* __restrict__ xbs,    // [Npad][128]  bf16 (self rows)
    const short* __restrict__ wb,     // [128][1152]  bf16
    const float* __restrict__ invdeg,
    float* __restrict__ out, int N)
{
  __shared__ char smem[65536];        // As0 16K | As1 16K | Bs0 16K | Bs1 16K
  char* As0 = smem;
  char* As1 = smem + 16384;
  char* Bs0 = smem + 32768;
  char* Bs1 = smem + 49152;

  const int tid  = threadIdx.x;
  const int lane = tid & 63;
  const int wid  = tid >> 6;          // 0..7
  const int wr   = wid >> 1;          // 0..3 : 32-row group
  const int wc   = wid & 1;           // 0..1 : 64-col group
  const int n0   = blockIdx.x * 128;
  const int lr   = lane & 15;
  const int lq   = lane >> 4;

  f32x4 acc[2][4];
  #pragma unroll
  for (int m = 0; m < 2; ++m)
    #pragma unroll
    for (int p = 0; p < 4; ++p)
      acc[m][p] = (f32x4){0.f, 0.f, 0.f, 0.f};

  const int srow = tid >> 3;   // 0..63
  const int scs  = tid & 7;

  auto STAGE = [&](char* Ab, char* Bb, int ks){
    const short* ab;
    size_t rstride;
    if (ks < 16){ ab = acat + (size_t)n0 * KR + ks * 64;          rstride = KR;  }
    else        { ab = xbs  + (size_t)n0 * 128 + (ks - 16) * 64;  rstride = 128; }
    #pragma unroll
    for (int q = 0; q < 2; ++q){
      int row = q * 64 + srow;
      const short* src = ab + (size_t)row * rstride + ((scs ^ (row & 7)) << 3);
      gload_lds16(src, Ab + q * 8192 + (wid << 10));
    }
    const short* bb = wb + ks * 64;
    #pragma unroll
    for (int q = 0; q < 2; ++q){
      int j = q * 64 + srow;
      const short* src = bb + (size_t)j * KCAT + ((scs ^ (j & 7)) << 3);
      gload_lds16(src, Bb + q * 8192 + (wid << 10));
    }
  };

  auto COMPUTE = [&](const char* Ab, const char* Bb){
    bf16x8 a[2][2], b[2][4];
    #pragma unroll
    for (int kk = 0; kk < 2; ++kk){
      #pragma unroll
      for (int m = 0; m < 2; ++m){
        int row = wr * 32 + m * 16 + lr;
        int c   = kk * 4 + lq;
        a[kk][m] = *(const bf16x8*)(Ab + row * 128 + ((c ^ (row & 7)) << 4));
      }
      #pragma unroll
      for (int p = 0; p < 4; ++p){
        int j = wc * 64 + p * 16 + lr;
        int c = kk * 4 + lq;
        b[kk][p] = *(const bf16x8*)(Bb + j * 128 + ((c ^ (j & 7)) << 4));
      }
    }
    #pragma unroll
    for (int kk = 0; kk < 2; ++kk)
      #pragma unroll
      for (int m = 0; m < 2; ++m)
        #pragma unroll
        for (int p = 0; p < 4; ++p)
          acc[m][p] = __builtin_amdgcn_mfma_f32_16x16x32_bf16(a[kk][m], b[kk][p], acc[m][p], 0, 0, 0);
  };

  STAGE(As0, Bs0, 0);
  __syncthreads();
  for (int ks = 0; ks < 18; ks += 2){
    STAGE(As1, Bs1, ks + 1);
    COMPUTE(As0, Bs0);
    __syncthreads();
    if (ks + 2 < 18) STAGE(As0, Bs0, ks + 2);
    COMPUTE(As1, Bs1);
    __syncthreads();
  }

  #pragma unroll
  for (int m = 0; m < 2; ++m){
    int rbase = n0 + wr * 32 + m * 16 + lq * 4;
    #pragma unroll
    for (int v = 0; v < 4; ++v){
      int ro = rbase + v;
      if (ro < N){
        float inv = invdeg[ro];
        #pragma unroll
        for (int p = 0; p < 4; ++p)
          __builtin_nontemporal_store(acc[m][p][v] * inv,
              &out[(((size_t)ro) << 7) + wc * 64 + p * 16 + lr]);
      }
    }
  }
}

extern "C" void kernel_launch(void* const* d_in, const int* in_sizes, int n_in,
                              void* d_out, int out_size, void* d_ws, size_t ws_size,
                              hipStream_t stream){
  const float* x  = (const float*)d_in[0];
  const int*   ei = (const int*)d_in[1];
  const int*   et = (const int*)d_in[2];
  const float* W  = (const float*)d_in[4];
  const float* W0 = (const float*)d_in[5];
  float* out = (float*)d_out;

  const int N = in_sizes[0] / NDIM;   // 50000
  const int E = in_sizes[2];          // 800000
  const int Npad = N + 128;           // BM=128 tail tile stays in-bounds
  const int nblkE = (E + EPB - 1) / EPB;   // 196

  char* ws = (char*)d_ws;
  size_t off = 0;
  auto alloc = [&](size_t bytes)->size_t{
    size_t p = off; off = (off + bytes + 255) & ~(size_t)255; return p;
  };
  size_t o_flag = alloc(4);
  size_t o_kv   = alloc((size_t)E * 4);
  size_t o_ct   = alloc((size_t)E);
  size_t o_ckv  = alloc((size_t)E * 4);
  size_t o_es   = alloc((size_t)E * 4);
  size_t o_cc   = alloc(COARSE * 4);
  size_t o_base = alloc((COARSE + 2) * 4);
  size_t o_br   = alloc((size_t)nblkE * COARSE * 4);
  size_t o_rs   = alloc((size_t)(N + 1) * 4);
  size_t o_inv  = alloc((size_t)N * 4);
  size_t o_h    = alloc((size_t)Npad * KR * 2);
  size_t o_wb   = alloc((size_t)NDIM * KCAT * 2);
  size_t o_xb   = alloc((size_t)Npad * NDIM * 2);   // padded for GEMM tail
  (void)ws_size;

  int*  flag   = (int*)(ws + o_flag);
  uint32* kv   = (uint32*)(ws + o_kv);
  unsigned char* ctmp = (unsigned char*)(ws + o_ct);
  uint32* ckv  = (uint32*)(ws + o_ckv);
  uint32* esort= (uint32*)(ws + o_es);
  int*  ccnt   = (int*)(ws + o_cc);
  int*  base   = (int*)(ws + o_base);
  int*  bres   = (int*)(ws + o_br);
  int*  rs     = (int*)(ws + o_rs);
  float* invdeg= (float*)(ws + o_inv);
  uint32* hcat = (uint32*)(ws + o_h);
  short* acat  = (short*)(ws + o_h);
  short* Wbs   = (short*)(ws + o_wb);
  uint32* xb   = (uint32*)(ws + o_xb);
  short* xbs   = (short*)(ws + o_xb);

  const int n4      = N * NDIM / 4;
  const int xblocks = (n4 + 255) / 256;             // 6250
  const int wblocks = (NDIM * KCAT + 255) / 256;    // 576

  k_prep<<<xblocks + wblocks + 1, 256, 0, stream>>>(
      x, xb, n4, xblocks, W, W0, Wbs, wblocks, ei, flag, ccnt);
  k_hist<<<nblkE, 1024, 0, stream>>>(ei, et, flag, kv, ctmp, ccnt, bres, E);
  k_base<<<1, 256, 0, stream>>>(ccnt, base);
  k_cscatter<<<nblkE, 1024, 0, stream>>>(kv, ctmp, base, bres, ckv, E);
  k_fine<<<COARSE, 1024, 0, stream>>>(ckv, base, esort, rs, N);
  k_agg<<<(N + 3) / 4, 256, 0, stream>>>(xb, rs, esort, hcat, invdeg, N);
  k_gemm2<<<(N + 127) / 128, 512, 0, stream>>>(acat, xbs, Wbs, invdeg, out, N);
}